// Round 1
// baseline (145.292 us; speedup 1.0000x reference)
//
#include <hip/hip_runtime.h>
#include <hip/hip_bf16.h>
#include <math.h>

// Problem constants (from the reference)
#define BB 512        // batch
#define CC 1000       // classes
#define TT 64         // num param tensors
#define PSZ 500000    // elements per tensor
#define NW 9          // loss weights per tensor

// Workspace layout (floats):
//  ws[0] = sum over batch of CE contributions  ( -(o_t - logZ) )
//  ws[1] = sum over batch of hinge row sums
//  ws[2] = sum over all (b,j) of logp
//  ws[3] = sum over batch of sum_j p*logp
//  ws[4] = sum over all (b,j) of o^2
//  ws[8 + t*4 + {0,1,2,3}] = {l1_zero, sumsq_zero, l1_pre, sumsq_pre} for tensor t
#define WS_FLOATS (8 + TT * 4)

// ---------------------------------------------------------------------------
// Block reduction helpers (256 threads = 4 waves of 64)
// ---------------------------------------------------------------------------
__device__ __forceinline__ float block_reduce_sum(float v, float* scratch) {
    __syncthreads();                       // protect scratch reuse
    for (int o = 32; o > 0; o >>= 1) v += __shfl_down(v, o);
    const int wave = threadIdx.x >> 6;
    if ((threadIdx.x & 63) == 0) scratch[wave] = v;
    __syncthreads();
    float r = scratch[0] + scratch[1] + scratch[2] + scratch[3];
    return r;
}

__device__ __forceinline__ float block_reduce_max(float v, float* scratch) {
    __syncthreads();
    for (int o = 32; o > 0; o >>= 1) v = fmaxf(v, __shfl_down(v, o));
    const int wave = threadIdx.x >> 6;
    if ((threadIdx.x & 63) == 0) scratch[wave] = v;
    __syncthreads();
    float r = fmaxf(fmaxf(scratch[0], scratch[1]), fmaxf(scratch[2], scratch[3]));
    return r;
}

// ---------------------------------------------------------------------------
// Kernel 1: per-tensor parameter norms (the HBM-bound 256 MB read)
// grid = (BLK_X, TT), block = 256
// ---------------------------------------------------------------------------
__global__ __launch_bounds__(256) void param_norms_kernel(
        const float* __restrict__ p, const float* __restrict__ q,
        float* __restrict__ ws) {
    const int t = blockIdx.y;
    const float4* __restrict__ p4 = (const float4*)(p + (long long)t * PSZ);
    const float4* __restrict__ q4 = (const float4*)(q + (long long)t * PSZ);
    const int n4 = PSZ / 4;  // 125000, P divisible by 4; base offset 16B-aligned

    float l1z = 0.f, s2z = 0.f, l1p = 0.f, s2p = 0.f;
    const int stride = gridDim.x * blockDim.x;
    for (int i = blockIdx.x * blockDim.x + threadIdx.x; i < n4; i += stride) {
        const float4 a = p4[i];
        const float4 c = q4[i];
        l1z += fabsf(a.x) + fabsf(a.y) + fabsf(a.z) + fabsf(a.w);
        s2z += a.x * a.x + a.y * a.y + a.z * a.z + a.w * a.w;
        const float dx = a.x - c.x, dy = a.y - c.y, dz = a.z - c.z, dw = a.w - c.w;
        l1p += fabsf(dx) + fabsf(dy) + fabsf(dz) + fabsf(dw);
        s2p += dx * dx + dy * dy + dz * dz + dw * dw;
    }
    // wave-level reduce, one atomic per wave per accumulator
    for (int o = 32; o > 0; o >>= 1) {
        l1z += __shfl_down(l1z, o);
        s2z += __shfl_down(s2z, o);
        l1p += __shfl_down(l1p, o);
        s2p += __shfl_down(s2p, o);
    }
    if ((threadIdx.x & 63) == 0) {
        float* base = ws + 8 + t * 4;
        atomicAdd(base + 0, l1z);
        atomicAdd(base + 1, s2z);
        atomicAdd(base + 2, l1p);
        atomicAdd(base + 3, s2p);
    }
}

// ---------------------------------------------------------------------------
// Kernel 2: logits losses, one block (256 threads) per batch row
// ---------------------------------------------------------------------------
__global__ __launch_bounds__(256) void logits_kernel(
        const float* __restrict__ out, const int* __restrict__ tgt,
        float* __restrict__ ws) {
    __shared__ float row[CC];
    __shared__ float scratch[4];
    const int b = blockIdx.x;
    const float* __restrict__ o = out + (long long)b * CC;

    float sq = 0.f;
    for (int j = threadIdx.x; j < CC; j += 256) {
        const float v = o[j];
        row[j] = v;
        sq += v * v;
    }
    __syncthreads();

    // row max
    float m = -3.402823466e+38f;
    for (int j = threadIdx.x; j < CC; j += 256) m = fmaxf(m, row[j]);
    m = block_reduce_max(m, scratch);

    // sum exp
    float se = 0.f;
    for (int j = threadIdx.x; j < CC; j += 256) se += __expf(row[j] - m);
    se = block_reduce_sum(se, scratch);
    const float logZ = m + __logf(se);

    const int tg = tgt[b];
    const float ot = row[tg];

    float ent = 0.f, lps = 0.f, hin = 0.f;
    for (int j = threadIdx.x; j < CC; j += 256) {
        const float lp = row[j] - logZ;
        ent += __expf(lp) * lp;
        lps += lp;
        const float mg = 1.f - ot + row[j];
        if (j != tg && mg > 0.f) hin += mg;
    }
    sq  = block_reduce_sum(sq, scratch);
    ent = block_reduce_sum(ent, scratch);
    lps = block_reduce_sum(lps, scratch);
    hin = block_reduce_sum(hin, scratch);

    if (threadIdx.x == 0) {
        atomicAdd(&ws[0], -(ot - logZ));  // CE contribution
        atomicAdd(&ws[1], hin);
        atomicAdd(&ws[2], lps);
        atomicAdd(&ws[3], ent);
        atomicAdd(&ws[4], sq);
    }
}

// ---------------------------------------------------------------------------
// Kernel 3: final combine — 64x9 sigmoid-weighted sum, one block
// ---------------------------------------------------------------------------
__global__ __launch_bounds__(256) void final_kernel(
        const float* __restrict__ lw, const float* __restrict__ ws,
        float* __restrict__ out) {
    __shared__ float scratch[4];
    const float ce      = ws[0] / (float)BB;
    const float hinge   = ws[1] / ((float)BB * (float)CC);
    const float kl      = -logf((float)CC) - ws[2] / ((float)BB * (float)CC);
    const float entropy = -ws[3] / (float)BB;
    const float energy  = sqrtf(ws[4]);
    const float glob[5] = {ce, hinge, kl, entropy, energy};

    float acc = 0.f;
    for (int i = threadIdx.x; i < TT * NW; i += 256) {
        const int t = i / NW;
        const int k = i - t * NW;
        float cmb;
        if (k < 5)       cmb = glob[k];
        else if (k == 5) cmb = ws[8 + t * 4 + 0];
        else if (k == 6) cmb = sqrtf(ws[8 + t * 4 + 1]);
        else if (k == 7) cmb = ws[8 + t * 4 + 2];
        else             cmb = sqrtf(ws[8 + t * 4 + 3]);
        const float w = 1.f / (1.f + expf(-lw[i]));
        acc += w * cmb;
    }
    acc = block_reduce_sum(acc, scratch);
    if (threadIdx.x == 0) out[0] = acc / (float)(TT * NW);
}

// ---------------------------------------------------------------------------
extern "C" void kernel_launch(void* const* d_in, const int* in_sizes, int n_in,
                              void* d_out, int out_size, void* d_ws, size_t ws_size,
                              hipStream_t stream) {
    const float* outputs    = (const float*)d_in[0];
    const int*   targets    = (const int*)d_in[1];
    const float* params     = (const float*)d_in[2];
    const float* pretrained = (const float*)d_in[3];
    const float* lw         = (const float*)d_in[4];
    float* ws  = (float*)d_ws;
    float* out = (float*)d_out;

    hipMemsetAsync(ws, 0, WS_FLOATS * sizeof(float), stream);

    // 32 blocks/tensor x 64 tensors = 2048 blocks x 4 waves = full occupancy
    param_norms_kernel<<<dim3(32, TT), 256, 0, stream>>>(params, pretrained, ws);
    logits_kernel<<<BB, 256, 0, stream>>>(outputs, targets, ws);
    final_kernel<<<1, 256, 0, stream>>>(lw, ws, out);
}

// Round 2
// 123.528 us; speedup vs baseline: 1.1762x; 1.1762x over previous
//
#include <hip/hip_runtime.h>
#include <hip/hip_bf16.h>
#include <math.h>

// Problem constants (from the reference)
#define BB 512        // batch
#define CC 1000       // classes
#define TT 64         // num param tensors
#define PSZ 500000    // elements per tensor
#define NW 9          // loss weights per tensor

#define N4 (PSZ / 4)          // 125000 float4 per tensor
#define PBLK_PER_T 32         // param blocks per tensor
#define PBLKS (TT * PBLK_PER_T)   // 2048
#define PSTRIDE (PBLK_PER_T * 256) // 8192 threads per tensor

// Workspace layout (floats):
//  ws[0] = sum_b CE contribution    ws[1] = sum_b hinge row sums
//  ws[2] = sum_{b,j} logp           ws[3] = sum_b sum_j p*logp
//  ws[4] = sum_{b,j} o^2
//  ws[8 + t*4 + {0,1,2,3}] = {l1_zero, sumsq_zero, l1_pre, sumsq_pre}
#define WS_FLOATS (8 + TT * 4)

// ---------------------------------------------------------------------------
__device__ __forceinline__ float block_reduce_sum(float v, float* scratch) {
    __syncthreads();
    for (int o = 32; o > 0; o >>= 1) v += __shfl_down(v, o);
    const int wave = threadIdx.x >> 6;
    if ((threadIdx.x & 63) == 0) scratch[wave] = v;
    __syncthreads();
    return scratch[0] + scratch[1] + scratch[2] + scratch[3];
}

__device__ __forceinline__ float block_reduce_max(float v, float* scratch) {
    __syncthreads();
    for (int o = 32; o > 0; o >>= 1) v = fmaxf(v, __shfl_down(v, o));
    const int wave = threadIdx.x >> 6;
    if ((threadIdx.x & 63) == 0) scratch[wave] = v;
    __syncthreads();
    return fmaxf(fmaxf(scratch[0], scratch[1]), fmaxf(scratch[2], scratch[3]));
}

// ---------------------------------------------------------------------------
// Fused kernel: blocks [0, 2048) do param norms, [2048, 2560) do logits rows.
// ---------------------------------------------------------------------------
__global__ __launch_bounds__(256) void fused_kernel(
        const float* __restrict__ p, const float* __restrict__ q,
        const float* __restrict__ outlog, const int* __restrict__ tgt,
        float* __restrict__ ws) {
    __shared__ float row[CC];
    __shared__ float scratch[4];

    const int bid = blockIdx.x;
    if (bid < PBLKS) {
        // ---------------- param-norm path (HBM-heavy, 256 MB total) --------
        const int t  = bid >> 5;          // tensor index
        const int bx = bid & 31;          // block-within-tensor
        const float4* __restrict__ p4 = (const float4*)(p + (long long)t * PSZ);
        const float4* __restrict__ q4 = (const float4*)(q + (long long)t * PSZ);

        float l1z = 0.f, s2z = 0.f, l1p = 0.f, s2p = 0.f;
        int i = bx * 256 + (int)threadIdx.x;

        // Manual 4x unroll: issue 8 independent float4 loads before any use.
        // This forces >=64 live VGPRs (defeats the VGPR=16 serialization seen
        // in round 1) and puts 8 KB/wave of memory in flight.
        while (i + 3 * PSTRIDE < N4) {
            const float4 a0 = p4[i];
            const float4 a1 = p4[i +     PSTRIDE];
            const float4 a2 = p4[i + 2 * PSTRIDE];
            const float4 a3 = p4[i + 3 * PSTRIDE];
            const float4 c0 = q4[i];
            const float4 c1 = q4[i +     PSTRIDE];
            const float4 c2 = q4[i + 2 * PSTRIDE];
            const float4 c3 = q4[i + 3 * PSTRIDE];

            l1z += fabsf(a0.x) + fabsf(a0.y) + fabsf(a0.z) + fabsf(a0.w)
                 + fabsf(a1.x) + fabsf(a1.y) + fabsf(a1.z) + fabsf(a1.w)
                 + fabsf(a2.x) + fabsf(a2.y) + fabsf(a2.z) + fabsf(a2.w)
                 + fabsf(a3.x) + fabsf(a3.y) + fabsf(a3.z) + fabsf(a3.w);
            s2z += a0.x*a0.x + a0.y*a0.y + a0.z*a0.z + a0.w*a0.w
                 + a1.x*a1.x + a1.y*a1.y + a1.z*a1.z + a1.w*a1.w
                 + a2.x*a2.x + a2.y*a2.y + a2.z*a2.z + a2.w*a2.w
                 + a3.x*a3.x + a3.y*a3.y + a3.z*a3.z + a3.w*a3.w;

            const float d0x = a0.x-c0.x, d0y = a0.y-c0.y, d0z = a0.z-c0.z, d0w = a0.w-c0.w;
            const float d1x = a1.x-c1.x, d1y = a1.y-c1.y, d1z = a1.z-c1.z, d1w = a1.w-c1.w;
            const float d2x = a2.x-c2.x, d2y = a2.y-c2.y, d2z = a2.z-c2.z, d2w = a2.w-c2.w;
            const float d3x = a3.x-c3.x, d3y = a3.y-c3.y, d3z = a3.z-c3.z, d3w = a3.w-c3.w;

            l1p += fabsf(d0x) + fabsf(d0y) + fabsf(d0z) + fabsf(d0w)
                 + fabsf(d1x) + fabsf(d1y) + fabsf(d1z) + fabsf(d1w)
                 + fabsf(d2x) + fabsf(d2y) + fabsf(d2z) + fabsf(d2w)
                 + fabsf(d3x) + fabsf(d3y) + fabsf(d3z) + fabsf(d3w);
            s2p += d0x*d0x + d0y*d0y + d0z*d0z + d0w*d0w
                 + d1x*d1x + d1y*d1y + d1z*d1z + d1w*d1w
                 + d2x*d2x + d2y*d2y + d2z*d2z + d2w*d2w
                 + d3x*d3x + d3y*d3y + d3z*d3z + d3w*d3w;

            i += 4 * PSTRIDE;
        }
        // tail (up to 3-4 strided steps, slightly divergent at the boundary)
        while (i < N4) {
            const float4 a = p4[i];
            const float4 c = q4[i];
            l1z += fabsf(a.x) + fabsf(a.y) + fabsf(a.z) + fabsf(a.w);
            s2z += a.x*a.x + a.y*a.y + a.z*a.z + a.w*a.w;
            const float dx = a.x-c.x, dy = a.y-c.y, dz = a.z-c.z, dw = a.w-c.w;
            l1p += fabsf(dx) + fabsf(dy) + fabsf(dz) + fabsf(dw);
            s2p += dx*dx + dy*dy + dz*dz + dw*dw;
            i += PSTRIDE;
        }

        for (int o = 32; o > 0; o >>= 1) {
            l1z += __shfl_down(l1z, o);
            s2z += __shfl_down(s2z, o);
            l1p += __shfl_down(l1p, o);
            s2p += __shfl_down(s2p, o);
        }
        if ((threadIdx.x & 63) == 0) {
            float* base = ws + 8 + t * 4;
            atomicAdd(base + 0, l1z);
            atomicAdd(base + 1, s2z);
            atomicAdd(base + 2, l1p);
            atomicAdd(base + 3, s2p);
        }
    } else {
        // ---------------- logits path (one block per batch row) ------------
        const int b = bid - PBLKS;
        const float* __restrict__ o = outlog + (long long)b * CC;

        float sq = 0.f;
        for (int j = threadIdx.x; j < CC; j += 256) {
            const float v = o[j];
            row[j] = v;
            sq += v * v;
        }
        __syncthreads();

        float m = -3.402823466e+38f;
        for (int j = threadIdx.x; j < CC; j += 256) m = fmaxf(m, row[j]);
        m = block_reduce_max(m, scratch);

        float se = 0.f;
        for (int j = threadIdx.x; j < CC; j += 256) se += __expf(row[j] - m);
        se = block_reduce_sum(se, scratch);
        const float logZ = m + __logf(se);

        const int tg = tgt[b];
        const float ot = row[tg];

        float ent = 0.f, lps = 0.f, hin = 0.f;
        for (int j = threadIdx.x; j < CC; j += 256) {
            const float lp = row[j] - logZ;
            ent += __expf(lp) * lp;
            lps += lp;
            const float mg = 1.f - ot + row[j];
            if (j != tg && mg > 0.f) hin += mg;
        }
        sq  = block_reduce_sum(sq, scratch);
        ent = block_reduce_sum(ent, scratch);
        lps = block_reduce_sum(lps, scratch);
        hin = block_reduce_sum(hin, scratch);

        if (threadIdx.x == 0) {
            atomicAdd(&ws[0], -(ot - logZ));
            atomicAdd(&ws[1], hin);
            atomicAdd(&ws[2], lps);
            atomicAdd(&ws[3], ent);
            atomicAdd(&ws[4], sq);
        }
    }
}

// ---------------------------------------------------------------------------
// Final combine — 64x9 sigmoid-weighted sum, one block
// ---------------------------------------------------------------------------
__global__ __launch_bounds__(256) void final_kernel(
        const float* __restrict__ lw, const float* __restrict__ ws,
        float* __restrict__ out) {
    __shared__ float scratch[4];
    const float ce      = ws[0] / (float)BB;
    const float hinge   = ws[1] / ((float)BB * (float)CC);
    const float kl      = -logf((float)CC) - ws[2] / ((float)BB * (float)CC);
    const float entropy = -ws[3] / (float)BB;
    const float energy  = sqrtf(ws[4]);
    const float glob[5] = {ce, hinge, kl, entropy, energy};

    float acc = 0.f;
    for (int i = threadIdx.x; i < TT * NW; i += 256) {
        const int t = i / NW;
        const int k = i - t * NW;
        float cmb;
        if (k < 5)       cmb = glob[k];
        else if (k == 5) cmb = ws[8 + t * 4 + 0];
        else if (k == 6) cmb = sqrtf(ws[8 + t * 4 + 1]);
        else if (k == 7) cmb = ws[8 + t * 4 + 2];
        else             cmb = sqrtf(ws[8 + t * 4 + 3]);
        const float w = 1.f / (1.f + expf(-lw[i]));
        acc += w * cmb;
    }
    acc = block_reduce_sum(acc, scratch);
    if (threadIdx.x == 0) out[0] = acc / (float)(TT * NW);
}

// ---------------------------------------------------------------------------
extern "C" void kernel_launch(void* const* d_in, const int* in_sizes, int n_in,
                              void* d_out, int out_size, void* d_ws, size_t ws_size,
                              hipStream_t stream) {
    const float* outputs    = (const float*)d_in[0];
    const int*   targets    = (const int*)d_in[1];
    const float* params     = (const float*)d_in[2];
    const float* pretrained = (const float*)d_in[3];
    const float* lw         = (const float*)d_in[4];
    float* ws  = (float*)d_ws;
    float* out = (float*)d_out;

    hipMemsetAsync(ws, 0, WS_FLOATS * sizeof(float), stream);

    // 2048 param blocks + 512 logits blocks in one dispatch
    fused_kernel<<<PBLKS + BB, 256, 0, stream>>>(params, pretrained, outputs, targets, ws);
    final_kernel<<<1, 256, 0, stream>>>(lw, ws, out);
}

// Round 3
// 121.515 us; speedup vs baseline: 1.1957x; 1.0166x over previous
//
#include <hip/hip_runtime.h>
#include <hip/hip_bf16.h>
#include <math.h>

// Problem constants (from the reference)
#define BB 512        // batch
#define CC 1000       // classes
#define TT 64         // num param tensors
#define PSZ 500000    // elements per tensor
#define NW 9          // loss weights per tensor

#define N4 (PSZ / 4)               // 125000 float4 per tensor
#define PBLK_PER_T 32              // param blocks per tensor
#define PBLKS (TT * PBLK_PER_T)    // 2048
#define PSTRIDE (PBLK_PER_T * 256) // 8192 threads per tensor
// 125000 = 15*8192 + 2120  -> every thread does k=0..14, threads with
// base < 2120 also do k=15.
#define KFULL 15
#define KTAIL (N4 - KFULL * PSTRIDE)   // 2120

// Workspace layout (floats):
//  ws[0] = sum_b CE contribution    ws[1] = sum_b hinge row sums
//  ws[2] = sum_{b,j} logp           ws[3] = sum_b sum_j p*logp
//  ws[4] = sum_{b,j} o^2
//  ws[8 + t*4 + {0,1,2,3}] = {l1_zero, sumsq_zero, l1_pre, sumsq_pre}
#define WS_FLOATS (8 + TT * 4)

// ---------------------------------------------------------------------------
__device__ __forceinline__ float block_reduce_sum(float v, float* scratch) {
    __syncthreads();
    for (int o = 32; o > 0; o >>= 1) v += __shfl_down(v, o);
    const int wave = threadIdx.x >> 6;
    if ((threadIdx.x & 63) == 0) scratch[wave] = v;
    __syncthreads();
    return scratch[0] + scratch[1] + scratch[2] + scratch[3];
}

__device__ __forceinline__ float block_reduce_max(float v, float* scratch) {
    __syncthreads();
    for (int o = 32; o > 0; o >>= 1) v = fmaxf(v, __shfl_down(v, o));
    const int wave = threadIdx.x >> 6;
    if ((threadIdx.x & 63) == 0) scratch[wave] = v;
    __syncthreads();
    return fmaxf(fmaxf(scratch[0], scratch[1]), fmaxf(scratch[2], scratch[3]));
}

// accumulate one (p, q) float4 pair into the four partials
__device__ __forceinline__ void acc4(const float4 a, const float4 c,
                                     float& l1z, float& s2z,
                                     float& l1p, float& s2p) {
    l1z += fabsf(a.x) + fabsf(a.y) + fabsf(a.z) + fabsf(a.w);
    s2z += a.x * a.x + a.y * a.y + a.z * a.z + a.w * a.w;
    const float dx = a.x - c.x, dy = a.y - c.y, dz = a.z - c.z, dw = a.w - c.w;
    l1p += fabsf(dx) + fabsf(dy) + fabsf(dz) + fabsf(dw);
    s2p += dx * dx + dy * dy + dz * dz + dw * dw;
}

// ---------------------------------------------------------------------------
// Fused kernel: blocks [0, 2048) do param norms, [2048, 2560) do logits rows.
// __launch_bounds__(256, 2): min 2 waves/EU -> VGPR cap 256, so the register
// allocator has no occupancy excuse to re-serialize the 8-deep load batches
// (round 2 came out at VGPR=32 => <=2 loads in flight; that was the bug).
// ---------------------------------------------------------------------------
__global__ __launch_bounds__(256, 2) void fused_kernel(
        const float* __restrict__ p, const float* __restrict__ q,
        const float* __restrict__ outlog, const int* __restrict__ tgt,
        float* __restrict__ ws) {
    __shared__ float row[CC];
    __shared__ float scratch[4];

    const int bid = blockIdx.x;
    if (bid < PBLKS) {
        // ---------------- param-norm path (256 MB total) -------------------
        const int t  = bid >> 5;          // tensor index
        const int bx = bid & 31;          // block-within-tensor
        const float4* __restrict__ p4 = (const float4*)(p + (long long)t * PSZ);
        const float4* __restrict__ q4 = (const float4*)(q + (long long)t * PSZ);
        const int i0 = bx * 256 + (int)threadIdx.x;   // 0..8191

        float l1z = 0.f, s2z = 0.f, l1p = 0.f, s2p = 0.f;
        float4 A[8], C[8];

        // ---- batch 1: k = 0..7 — 16 straight-line loads, then consume ----
        #pragma unroll
        for (int k = 0; k < 8; ++k) A[k] = p4[i0 + k * PSTRIDE];
        #pragma unroll
        for (int k = 0; k < 8; ++k) C[k] = q4[i0 + k * PSTRIDE];
        #pragma unroll
        for (int k = 0; k < 8; ++k) acc4(A[k], C[k], l1z, s2z, l1p, s2p);

        // ---- batch 2: k = 8..14 — 14 straight-line loads, then consume ---
        #pragma unroll
        for (int k = 0; k < 7; ++k) A[k] = p4[i0 + (8 + k) * PSTRIDE];
        #pragma unroll
        for (int k = 0; k < 7; ++k) C[k] = q4[i0 + (8 + k) * PSTRIDE];
        #pragma unroll
        for (int k = 0; k < 7; ++k) acc4(A[k], C[k], l1z, s2z, l1p, s2p);

        // ---- tail: first KTAIL threads of the tensor do k = 15 -----------
        if (i0 < KTAIL) {
            const float4 a = p4[i0 + KFULL * PSTRIDE];
            const float4 c = q4[i0 + KFULL * PSTRIDE];
            acc4(a, c, l1z, s2z, l1p, s2p);
        }

        for (int o = 32; o > 0; o >>= 1) {
            l1z += __shfl_down(l1z, o);
            s2z += __shfl_down(s2z, o);
            l1p += __shfl_down(l1p, o);
            s2p += __shfl_down(s2p, o);
        }
        if ((threadIdx.x & 63) == 0) {
            float* base = ws + 8 + t * 4;
            atomicAdd(base + 0, l1z);
            atomicAdd(base + 1, s2z);
            atomicAdd(base + 2, l1p);
            atomicAdd(base + 3, s2p);
        }
    } else {
        // ---------------- logits path (one block per batch row) ------------
        const int b = bid - PBLKS;
        const float* __restrict__ o = outlog + (long long)b * CC;

        float sq = 0.f;
        for (int j = threadIdx.x; j < CC; j += 256) {
            const float v = o[j];
            row[j] = v;
            sq += v * v;
        }
        __syncthreads();

        float m = -3.402823466e+38f;
        for (int j = threadIdx.x; j < CC; j += 256) m = fmaxf(m, row[j]);
        m = block_reduce_max(m, scratch);

        float se = 0.f;
        for (int j = threadIdx.x; j < CC; j += 256) se += __expf(row[j] - m);
        se = block_reduce_sum(se, scratch);
        const float logZ = m + __logf(se);

        const int tg = tgt[b];
        const float ot = row[tg];

        float ent = 0.f, lps = 0.f, hin = 0.f;
        for (int j = threadIdx.x; j < CC; j += 256) {
            const float lp = row[j] - logZ;
            ent += __expf(lp) * lp;
            lps += lp;
            const float mg = 1.f - ot + row[j];
            if (j != tg && mg > 0.f) hin += mg;
        }
        sq  = block_reduce_sum(sq, scratch);
        ent = block_reduce_sum(ent, scratch);
        lps = block_reduce_sum(lps, scratch);
        hin = block_reduce_sum(hin, scratch);

        if (threadIdx.x == 0) {
            atomicAdd(&ws[0], -(ot - logZ));
            atomicAdd(&ws[1], hin);
            atomicAdd(&ws[2], lps);
            atomicAdd(&ws[3], ent);
            atomicAdd(&ws[4], sq);
        }
    }
}

// ---------------------------------------------------------------------------
// Final combine — 64x9 sigmoid-weighted sum, one block
// ---------------------------------------------------------------------------
__global__ __launch_bounds__(256) void final_kernel(
        const float* __restrict__ lw, const float* __restrict__ ws,
        float* __restrict__ out) {
    __shared__ float scratch[4];
    const float ce      = ws[0] / (float)BB;
    const float hinge   = ws[1] / ((float)BB * (float)CC);
    const float kl      = -logf((float)CC) - ws[2] / ((float)BB * (float)CC);
    const float entropy = -ws[3] / (float)BB;
    const float energy  = sqrtf(ws[4]);
    const float glob[5] = {ce, hinge, kl, entropy, energy};

    float acc = 0.f;
    for (int i = threadIdx.x; i < TT * NW; i += 256) {
        const int t = i / NW;
        const int k = i - t * NW;
        float cmb;
        if (k < 5)       cmb = glob[k];
        else if (k == 5) cmb = ws[8 + t * 4 + 0];
        else if (k == 6) cmb = sqrtf(ws[8 + t * 4 + 1]);
        else if (k == 7) cmb = ws[8 + t * 4 + 2];
        else             cmb = sqrtf(ws[8 + t * 4 + 3]);
        const float w = 1.f / (1.f + expf(-lw[i]));
        acc += w * cmb;
    }
    acc = block_reduce_sum(acc, scratch);
    if (threadIdx.x == 0) out[0] = acc / (float)(TT * NW);
}

// ---------------------------------------------------------------------------
extern "C" void kernel_launch(void* const* d_in, const int* in_sizes, int n_in,
                              void* d_out, int out_size, void* d_ws, size_t ws_size,
                              hipStream_t stream) {
    const float* outputs    = (const float*)d_in[0];
    const int*   targets    = (const int*)d_in[1];
    const float* params     = (const float*)d_in[2];
    const float* pretrained = (const float*)d_in[3];
    const float* lw         = (const float*)d_in[4];
    float* ws  = (float*)d_ws;
    float* out = (float*)d_out;

    hipMemsetAsync(ws, 0, WS_FLOATS * sizeof(float), stream);

    // 2048 param blocks + 512 logits blocks in one dispatch
    fused_kernel<<<PBLKS + BB, 256, 0, stream>>>(params, pretrained, outputs, targets, ws);
    final_kernel<<<1, 256, 0, stream>>>(lw, ws, out);
}

// Round 4
// 114.052 us; speedup vs baseline: 1.2739x; 1.0654x over previous
//
#include <hip/hip_runtime.h>
#include <hip/hip_bf16.h>
#include <math.h>

// Problem constants (from the reference)
#define BB 512        // batch
#define CC 1000       // classes
#define TT 64         // num param tensors
#define PSZ 500000    // elements per tensor
#define NW 9          // loss weights per tensor

#define N4 (PSZ / 4)               // 125000 float4 per tensor
#define PBLK_PER_T 32              // param blocks per tensor
#define PBLKS (TT * PBLK_PER_T)    // 2048
#define PSTRIDE (PBLK_PER_T * 256) // 8192 threads per tensor
// 125000 = 15*8192 + 2120
#define KFULL 15
#define KTAIL (N4 - KFULL * PSTRIDE)   // 2120

// Workspace layout (floats):
//  ws[0] = sum_b CE contribution    ws[1] = sum_b hinge row sums
//  ws[2] = sum_{b,j} logp           ws[3] = sum_b sum_j p*logp
//  ws[4] = sum_{b,j} o^2
//  ws[8 + t*4 + {0,1,2,3}] = {l1_zero, sumsq_zero, l1_pre, sumsq_pre}
#define WS_FLOATS (8 + TT * 4)

typedef float f32x4 __attribute__((ext_vector_type(4)));

__device__ __forceinline__ f32x4 ntload(const f32x4* a) {
    // non-temporal: no L2/L3 allocation. The 258 MB stream straddles the
    // 256 MB Infinity Cache; allocating it evict+fills the whole L3 every
    // pass (suspected serializer behind the flat ~2 TB/s).
    return __builtin_nontemporal_load(a);
}

// ---------------------------------------------------------------------------
__device__ __forceinline__ float block_reduce_sum(float v, float* scratch) {
    __syncthreads();
    for (int o = 32; o > 0; o >>= 1) v += __shfl_down(v, o);
    const int wave = threadIdx.x >> 6;
    if ((threadIdx.x & 63) == 0) scratch[wave] = v;
    __syncthreads();
    return scratch[0] + scratch[1] + scratch[2] + scratch[3];
}

__device__ __forceinline__ float block_reduce_max(float v, float* scratch) {
    __syncthreads();
    for (int o = 32; o > 0; o >>= 1) v = fmaxf(v, __shfl_down(v, o));
    const int wave = threadIdx.x >> 6;
    if ((threadIdx.x & 63) == 0) scratch[wave] = v;
    __syncthreads();
    return fmaxf(fmaxf(scratch[0], scratch[1]), fmaxf(scratch[2], scratch[3]));
}

// accumulate one (p, q) float4 pair into the four partials
__device__ __forceinline__ void acc4(const f32x4 a, const f32x4 c,
                                     float& l1z, float& s2z,
                                     float& l1p, float& s2p) {
    l1z += fabsf(a.x) + fabsf(a.y) + fabsf(a.z) + fabsf(a.w);
    s2z += a.x * a.x + a.y * a.y + a.z * a.z + a.w * a.w;
    const float dx = a.x - c.x, dy = a.y - c.y, dz = a.z - c.z, dw = a.w - c.w;
    l1p += fabsf(dx) + fabsf(dy) + fabsf(dz) + fabsf(dw);
    s2p += dx * dx + dy * dy + dz * dz + dw * dw;
}

// ---------------------------------------------------------------------------
// Fused kernel: blocks [0, 2048) do param norms, [2048, 2560) do logits rows.
// Param path: ALL 30 loads of a thread issued straight-line (nt) before any
// consume -> ~30 KB/wave in flight, the maximum-MLP configuration.
// ---------------------------------------------------------------------------
__global__ __launch_bounds__(256, 2) void fused_kernel(
        const float* __restrict__ p, const float* __restrict__ q,
        const float* __restrict__ outlog, const int* __restrict__ tgt,
        float* __restrict__ ws) {
    __shared__ float row[CC];
    __shared__ float scratch[4];

    const int bid = blockIdx.x;
    if (bid < PBLKS) {
        // ---------------- param-norm path (256 MB total) -------------------
        const int t  = bid >> 5;
        const int bx = bid & 31;
        const f32x4* __restrict__ p4 = (const f32x4*)(p + (long long)t * PSZ);
        const f32x4* __restrict__ q4 = (const f32x4*)(q + (long long)t * PSZ);
        const int i0 = bx * 256 + (int)threadIdx.x;   // 0..8191

        float l1z = 0.f, s2z = 0.f, l1p = 0.f, s2p = 0.f;
        f32x4 A[KFULL], C[KFULL];

        #pragma unroll
        for (int k = 0; k < KFULL; ++k) A[k] = ntload(p4 + i0 + k * PSTRIDE);
        #pragma unroll
        for (int k = 0; k < KFULL; ++k) C[k] = ntload(q4 + i0 + k * PSTRIDE);
        #pragma unroll
        for (int k = 0; k < KFULL; ++k) acc4(A[k], C[k], l1z, s2z, l1p, s2p);

        // tail: first KTAIL threads of the tensor do k = 15
        if (i0 < KTAIL) {
            const f32x4 a = ntload(p4 + i0 + KFULL * PSTRIDE);
            const f32x4 c = ntload(q4 + i0 + KFULL * PSTRIDE);
            acc4(a, c, l1z, s2z, l1p, s2p);
        }

        for (int o = 32; o > 0; o >>= 1) {
            l1z += __shfl_down(l1z, o);
            s2z += __shfl_down(s2z, o);
            l1p += __shfl_down(l1p, o);
            s2p += __shfl_down(s2p, o);
        }
        if ((threadIdx.x & 63) == 0) {
            float* base = ws + 8 + t * 4;
            atomicAdd(base + 0, l1z);
            atomicAdd(base + 1, s2z);
            atomicAdd(base + 2, l1p);
            atomicAdd(base + 3, s2p);
        }
    } else {
        // ---------------- logits path (one block per batch row) ------------
        const int b = bid - PBLKS;
        const float* __restrict__ o = outlog + (long long)b * CC;

        float sq = 0.f;
        for (int j = threadIdx.x; j < CC; j += 256) {
            const float v = o[j];
            row[j] = v;
            sq += v * v;
        }
        __syncthreads();

        float m = -3.402823466e+38f;
        for (int j = threadIdx.x; j < CC; j += 256) m = fmaxf(m, row[j]);
        m = block_reduce_max(m, scratch);

        float se = 0.f;
        for (int j = threadIdx.x; j < CC; j += 256) se += __expf(row[j] - m);
        se = block_reduce_sum(se, scratch);
        const float logZ = m + __logf(se);

        const int tg = tgt[b];
        const float ot = row[tg];

        float ent = 0.f, lps = 0.f, hin = 0.f;
        for (int j = threadIdx.x; j < CC; j += 256) {
            const float lp = row[j] - logZ;
            ent += __expf(lp) * lp;
            lps += lp;
            const float mg = 1.f - ot + row[j];
            if (j != tg && mg > 0.f) hin += mg;
        }
        sq  = block_reduce_sum(sq, scratch);
        ent = block_reduce_sum(ent, scratch);
        lps = block_reduce_sum(lps, scratch);
        hin = block_reduce_sum(hin, scratch);

        if (threadIdx.x == 0) {
            atomicAdd(&ws[0], -(ot - logZ));
            atomicAdd(&ws[1], hin);
            atomicAdd(&ws[2], lps);
            atomicAdd(&ws[3], ent);
            atomicAdd(&ws[4], sq);
        }
    }
}

// ---------------------------------------------------------------------------
// Final combine — 64x9 sigmoid-weighted sum, one block
// ---------------------------------------------------------------------------
__global__ __launch_bounds__(256) void final_kernel(
        const float* __restrict__ lw, const float* __restrict__ ws,
        float* __restrict__ out) {
    __shared__ float scratch[4];
    const float ce      = ws[0] / (float)BB;
    const float hinge   = ws[1] / ((float)BB * (float)CC);
    const float kl      = -logf((float)CC) - ws[2] / ((float)BB * (float)CC);
    const float entropy = -ws[3] / (float)BB;
    const float energy  = sqrtf(ws[4]);
    const float glob[5] = {ce, hinge, kl, entropy, energy};

    float acc = 0.f;
    for (int i = threadIdx.x; i < TT * NW; i += 256) {
        const int t = i / NW;
        const int k = i - t * NW;
        float cmb;
        if (k < 5)       cmb = glob[k];
        else if (k == 5) cmb = ws[8 + t * 4 + 0];
        else if (k == 6) cmb = sqrtf(ws[8 + t * 4 + 1]);
        else if (k == 7) cmb = ws[8 + t * 4 + 2];
        else             cmb = sqrtf(ws[8 + t * 4 + 3]);
        const float w = 1.f / (1.f + expf(-lw[i]));
        acc += w * cmb;
    }
    acc = block_reduce_sum(acc, scratch);
    if (threadIdx.x == 0) out[0] = acc / (float)(TT * NW);
}

// ---------------------------------------------------------------------------
extern "C" void kernel_launch(void* const* d_in, const int* in_sizes, int n_in,
                              void* d_out, int out_size, void* d_ws, size_t ws_size,
                              hipStream_t stream) {
    const float* outputs    = (const float*)d_in[0];
    const int*   targets    = (const int*)d_in[1];
    const float* params     = (const float*)d_in[2];
    const float* pretrained = (const float*)d_in[3];
    const float* lw         = (const float*)d_in[4];
    float* ws  = (float*)d_ws;
    float* out = (float*)d_out;

    hipMemsetAsync(ws, 0, WS_FLOATS * sizeof(float), stream);

    // 2048 param blocks + 512 logits blocks in one dispatch
    fused_kernel<<<PBLKS + BB, 256, 0, stream>>>(params, pretrained, outputs, targets, ws);
    final_kernel<<<1, 256, 0, stream>>>(lw, ws, out);
}

// Round 5
// 89.086 us; speedup vs baseline: 1.6309x; 1.2803x over previous
//
#include <hip/hip_runtime.h>
#include <hip/hip_bf16.h>
#include <math.h>

// Problem constants (from the reference)
#define BB 512        // batch
#define CC 1000       // classes
#define TT 64         // num param tensors
#define PSZ 500000    // elements per tensor
#define NW 9          // loss weights per tensor

// Param decomposition: 20 blocks per tensor, each owning a CONTIGUOUS chunk.
// 500000 floats / 20 = 25000 floats = 6250 float4 per block.
// 6250 = 3 * 2048 + 106  -> 3 bursts of (8 x 256 float4) + 106-float4 tail.
#define BPT 20
#define PBLKS (TT * BPT)       // 1280
#define C4 6250                // float4 per block chunk
#define TAIL4 106              // 6250 - 3*2048

// Workspace layout (floats):
//  ws[0] = sum_b CE contribution    ws[1] = sum_b hinge row sums
//  ws[2] = sum_{b,j} logp           ws[3] = sum_b sum_j p*logp
//  ws[4] = sum_{b,j} o^2
//  ws[8 + t*4 + {0,1,2,3}] = {l1_zero, sumsq_zero, l1_pre, sumsq_pre}
#define WS_FLOATS (8 + TT * 4)

typedef float f32x4 __attribute__((ext_vector_type(4)));

__device__ __forceinline__ f32x4 ntload(const f32x4* a) {
    return __builtin_nontemporal_load(a);
}

// ---------------------------------------------------------------------------
__device__ __forceinline__ float block_reduce_sum(float v, float* scratch) {
    __syncthreads();
    for (int o = 32; o > 0; o >>= 1) v += __shfl_down(v, o);
    const int wave = threadIdx.x >> 6;
    if ((threadIdx.x & 63) == 0) scratch[wave] = v;
    __syncthreads();
    return scratch[0] + scratch[1] + scratch[2] + scratch[3];
}

__device__ __forceinline__ float block_reduce_max(float v, float* scratch) {
    __syncthreads();
    for (int o = 32; o > 0; o >>= 1) v = fmaxf(v, __shfl_down(v, o));
    const int wave = threadIdx.x >> 6;
    if ((threadIdx.x & 63) == 0) scratch[wave] = v;
    __syncthreads();
    return fmaxf(fmaxf(scratch[0], scratch[1]), fmaxf(scratch[2], scratch[3]));
}

__device__ __forceinline__ void acc4(const f32x4 a, const f32x4 c,
                                     float& l1z, float& s2z,
                                     float& l1p, float& s2p) {
    l1z += fabsf(a.x) + fabsf(a.y) + fabsf(a.z) + fabsf(a.w);
    s2z += a.x * a.x + a.y * a.y + a.z * a.z + a.w * a.w;
    const float dx = a.x - c.x, dy = a.y - c.y, dz = a.z - c.z, dw = a.w - c.w;
    l1p += fabsf(dx) + fabsf(dy) + fabsf(dz) + fabsf(dw);
    s2p += dx * dx + dy * dy + dz * dz + dw * dw;
}

// ---------------------------------------------------------------------------
// Fused kernel: blocks [0, 1280) param norms (contiguous chunks, burst reads),
//               blocks [1280, 1792) logits rows.
// ---------------------------------------------------------------------------
__global__ __launch_bounds__(256) void fused_kernel(
        const float* __restrict__ p, const float* __restrict__ q,
        const float* __restrict__ outlog, const int* __restrict__ tgt,
        float* __restrict__ ws) {
    __shared__ float row[CC];
    __shared__ float scratch[4];

    const int bid = blockIdx.x;
    const int tid = (int)threadIdx.x;
    if (bid < PBLKS) {
        // ---------------- param-norm path (256 MB total) -------------------
        // Block bid owns contiguous float4 range [bid*C4, (bid+1)*C4), which
        // lies entirely inside tensor t = bid/BPT. Access order within the
        // block is SEQUENTIAL: bursts of 8 consecutive 1 KB wave-lines from
        // p, then the matching 8 KB from q (copy-kernel-like pattern; the
        // 128 KB-strided walk of rounds 1-4 sat flat at ~2.4 TB/s).
        const int t = bid / BPT;
        const f32x4* __restrict__ pb = (const f32x4*)p + (long long)bid * C4;
        const f32x4* __restrict__ qb = (const f32x4*)q + (long long)bid * C4;

        float l1z = 0.f, s2z = 0.f, l1p = 0.f, s2p = 0.f;
        f32x4 A[8], C[8];

        #pragma unroll 1
        for (int j = 0; j < 3; ++j) {
            const f32x4* bp = pb + j * 2048 + tid;
            const f32x4* bq = qb + j * 2048 + tid;
            #pragma unroll
            for (int k = 0; k < 8; ++k) A[k] = ntload(bp + k * 256);
            #pragma unroll
            for (int k = 0; k < 8; ++k) C[k] = ntload(bq + k * 256);
            #pragma unroll
            for (int k = 0; k < 8; ++k) acc4(A[k], C[k], l1z, s2z, l1p, s2p);
        }
        // tail: 106 float4 at chunk offset 6144
        if (tid < TAIL4) {
            const f32x4 a = ntload(pb + 3 * 2048 + tid);
            const f32x4 c = ntload(qb + 3 * 2048 + tid);
            acc4(a, c, l1z, s2z, l1p, s2p);
        }

        for (int o = 32; o > 0; o >>= 1) {
            l1z += __shfl_down(l1z, o);
            s2z += __shfl_down(s2z, o);
            l1p += __shfl_down(l1p, o);
            s2p += __shfl_down(s2p, o);
        }
        if ((tid & 63) == 0) {
            float* base = ws + 8 + t * 4;
            atomicAdd(base + 0, l1z);
            atomicAdd(base + 1, s2z);
            atomicAdd(base + 2, l1p);
            atomicAdd(base + 3, s2p);
        }
    } else {
        // ---------------- logits path (one block per batch row) ------------
        const int b = bid - PBLKS;
        const float* __restrict__ o = outlog + (long long)b * CC;

        float sq = 0.f;
        for (int j = tid; j < CC; j += 256) {
            const float v = o[j];
            row[j] = v;
            sq += v * v;
        }
        __syncthreads();

        float m = -3.402823466e+38f;
        for (int j = tid; j < CC; j += 256) m = fmaxf(m, row[j]);
        m = block_reduce_max(m, scratch);

        float se = 0.f;
        for (int j = tid; j < CC; j += 256) se += __expf(row[j] - m);
        se = block_reduce_sum(se, scratch);
        const float logZ = m + __logf(se);

        const int tg = tgt[b];
        const float ot = row[tg];

        float ent = 0.f, lps = 0.f, hin = 0.f;
        for (int j = tid; j < CC; j += 256) {
            const float lp = row[j] - logZ;
            ent += __expf(lp) * lp;
            lps += lp;
            const float mg = 1.f - ot + row[j];
            if (j != tg && mg > 0.f) hin += mg;
        }
        sq  = block_reduce_sum(sq, scratch);
        ent = block_reduce_sum(ent, scratch);
        lps = block_reduce_sum(lps, scratch);
        hin = block_reduce_sum(hin, scratch);

        if (tid == 0) {
            atomicAdd(&ws[0], -(ot - logZ));
            atomicAdd(&ws[1], hin);
            atomicAdd(&ws[2], lps);
            atomicAdd(&ws[3], ent);
            atomicAdd(&ws[4], sq);
        }
    }
}

// ---------------------------------------------------------------------------
// Final combine — 64x9 sigmoid-weighted sum, one block
// ---------------------------------------------------------------------------
__global__ __launch_bounds__(256) void final_kernel(
        const float* __restrict__ lw, const float* __restrict__ ws,
        float* __restrict__ out) {
    __shared__ float scratch[4];
    const float ce      = ws[0] / (float)BB;
    const float hinge   = ws[1] / ((float)BB * (float)CC);
    const float kl      = -logf((float)CC) - ws[2] / ((float)BB * (float)CC);
    const float entropy = -ws[3] / (float)BB;
    const float energy  = sqrtf(ws[4]);
    const float glob[5] = {ce, hinge, kl, entropy, energy};

    float acc = 0.f;
    for (int i = threadIdx.x; i < TT * NW; i += 256) {
        const int t = i / NW;
        const int k = i - t * NW;
        float cmb;
        if (k < 5)       cmb = glob[k];
        else if (k == 5) cmb = ws[8 + t * 4 + 0];
        else if (k == 6) cmb = sqrtf(ws[8 + t * 4 + 1]);
        else if (k == 7) cmb = ws[8 + t * 4 + 2];
        else             cmb = sqrtf(ws[8 + t * 4 + 3]);
        const float w = 1.f / (1.f + expf(-lw[i]));
        acc += w * cmb;
    }
    acc = block_reduce_sum(acc, scratch);
    if (threadIdx.x == 0) out[0] = acc / (float)(TT * NW);
}

// ---------------------------------------------------------------------------
extern "C" void kernel_launch(void* const* d_in, const int* in_sizes, int n_in,
                              void* d_out, int out_size, void* d_ws, size_t ws_size,
                              hipStream_t stream) {
    const float* outputs    = (const float*)d_in[0];
    const int*   targets    = (const int*)d_in[1];
    const float* params     = (const float*)d_in[2];
    const float* pretrained = (const float*)d_in[3];
    const float* lw         = (const float*)d_in[4];
    float* ws  = (float*)d_ws;
    float* out = (float*)d_out;

    hipMemsetAsync(ws, 0, WS_FLOATS * sizeof(float), stream);

    // 1280 param blocks (contiguous chunks) + 512 logits blocks
    fused_kernel<<<PBLKS + BB, 256, 0, stream>>>(params, pretrained, outputs, targets, ws);
    final_kernel<<<1, 256, 0, stream>>>(lw, ws, out);
}